// Round 9
// baseline (435.153 us; speedup 1.0000x reference)
//
#include <hip/hip_runtime.h>
#include <hip/hip_bf16.h>
#include <cstdint>

typedef __bf16 bf16x8 __attribute__((ext_vector_type(8)));
typedef __bf16 bf16x4 __attribute__((ext_vector_type(4)));
typedef float  f32x4  __attribute__((ext_vector_type(4)));
typedef float  f32x16 __attribute__((ext_vector_type(16)));
typedef unsigned u32x4 __attribute__((ext_vector_type(4)));

__device__ __forceinline__ f32x4 mfma16(bf16x8 a, bf16x8 b, f32x4 c) {
  return __builtin_amdgcn_mfma_f32_16x16x32_bf16(a, b, c, 0, 0, 0);
}
__device__ __forceinline__ f32x16 mfma32(bf16x8 a, bf16x8 b, f32x16 c) {
  return __builtin_amdgcn_mfma_f32_32x32x16_bf16(a, b, c, 0, 0, 0);
}

__device__ __forceinline__ void gload_lds16(const __bf16* g, __bf16* l) {
  __builtin_amdgcn_global_load_lds(
      (const __attribute__((address_space(1))) void*)g,
      (__attribute__((address_space(3))) void*)l, 16, 0, 0);
}

__device__ __forceinline__ unsigned cvtpk(float lo, float hi) {
  unsigned r;
  asm("v_cvt_pk_bf16_f32 %0, %1, %2" : "=v"(r) : "v"(lo), "v"(hi));
  return r;
}
__device__ __forceinline__ void plswap(unsigned& a, unsigned& b) {
  asm("v_permlane32_swap_b32 %0, %1" : "+v"(a), "+v"(b));
}

// ---------------- fp32 -> bf16 convert (x4 per thread) ----------------
__global__ __launch_bounds__(256) void cvt_bf16_kernel(const float* __restrict__ in,
                                                       __bf16* __restrict__ out, int n4) {
  int i = blockIdx.x * 256 + threadIdx.x;
  if (i < n4) {
    float4 v = ((const float4*)in)[i];
    bf16x4 o;
    o[0] = (__bf16)v.x; o[1] = (__bf16)v.y; o[2] = (__bf16)v.z; o[3] = (__bf16)v.w;
    ((bf16x4*)out)[i] = o;
  }
}

// ------------- transpose + cvt: src (R x C) f32 -> dst (C x R) bf16 -------------
__global__ __launch_bounds__(256) void transpose_cvt_kernel(const float* __restrict__ src,
                                                            __bf16* __restrict__ dst,
                                                            int R, int C) {
  __shared__ float tile[32][33];
  int r0 = blockIdx.y * 32, c0 = blockIdx.x * 32;
  int tx = threadIdx.x & 31, ty = threadIdx.x >> 5;
#pragma unroll
  for (int i = 0; i < 4; ++i)
    tile[ty + i * 8][tx] = src[(size_t)(r0 + ty + i * 8) * C + c0 + tx];
  __syncthreads();
#pragma unroll
  for (int i = 0; i < 4; ++i) {
    int rr = ty + i * 8;
    dst[(size_t)(c0 + rr) * R + r0 + tx] = (__bf16)tile[tx][rr];
  }
}

// ------------- bf16 GEMM, A (MxK) row-major, Bt (NxK) row-major = B^T -------------
// AUG=1: q/k written chunk-major augmented layout [bh][12][512][8].
template <int EPI, int AUG>
__global__ __launch_bounds__(256) void gemm_bt_kernel(
    const __bf16* __restrict__ A, const __bf16* __restrict__ Bt,
    int M, int N, int K, int nbx,
    const float* __restrict__ bias,
    float* __restrict__ outF,
    __bf16* __restrict__ qo, __bf16* __restrict__ ko, __bf16* __restrict__ vTo,
    int vstride) {
  __shared__ __attribute__((aligned(16))) __bf16 lds[2][2][4096];  // [buf][A/B][128*32]
  const int t = threadIdx.x;
  const int l = t & 63, w = t >> 6;
  const int wm = (w >> 1) * 64, wn = (w & 1) * 64;
  const int cpx = gridDim.x >> 3;
  const int wg = (blockIdx.x & 7) * cpx + (blockIdx.x >> 3);
  const int m0 = (wg / nbx) * 128, n0 = (wg % nbx) * 128;
  const int nk = K >> 5;

  auto stage = [&](int buf, int kt) {
    const __bf16* As = A + (size_t)m0 * K + kt * 32;
    const __bf16* Bs = Bt + (size_t)n0 * K + kt * 32;
#pragma unroll
    for (int rnd = 0; rnd < 2; ++rnd) {
      int li = rnd * 256 + t;
      int row = li >> 2, c8 = (li & 3) * 8;
      gload_lds16(As + (size_t)row * K + c8, &lds[buf][0][li * 8]);
      gload_lds16(Bs + (size_t)row * K + c8, &lds[buf][1][li * 8]);
    }
  };

  f32x4 acc[4][4] = {};
  stage(0, 0);
  __syncthreads();
  int buf = 0;
  for (int kt = 0; kt < nk; ++kt) {
    if (kt + 1 < nk) stage(buf ^ 1, kt + 1);
    bf16x8 af[4], bfv[4];
    const __bf16* la = &lds[buf][0][0];
    const __bf16* lb = &lds[buf][1][0];
#pragma unroll
    for (int mt = 0; mt < 4; ++mt)
      af[mt] = *(const bf16x8*)(la + (wm + mt * 16 + (l & 15)) * 32 + (l >> 4) * 8);
#pragma unroll
    for (int nt = 0; nt < 4; ++nt)
      bfv[nt] = *(const bf16x8*)(lb + (wn + nt * 16 + (l & 15)) * 32 + (l >> 4) * 8);
#pragma unroll
    for (int mt = 0; mt < 4; ++mt)
#pragma unroll
      for (int nt = 0; nt < 4; ++nt)
        acc[mt][nt] = mfma16(af[mt], bfv[nt], acc[mt][nt]);
    __syncthreads();
    buf ^= 1;
  }

#pragma unroll
  for (int mt = 0; mt < 4; ++mt) {
#pragma unroll
    for (int nt = 0; nt < 4; ++nt) {
#pragma unroll
      for (int r = 0; r < 4; ++r) {
        int row = m0 + wm + mt * 16 + (l >> 4) * 4 + r;
        int col = n0 + wn + nt * 16 + (l & 15);
        float val = acc[mt][nt][r] + bias[col];
        if constexpr (EPI == 0) {
          int s = col / 768, rem = col - s * 768;
          int h = rem >> 6, c = rem & 63;
          int b = row >> 9, n = row & 511;
          size_t bh = (size_t)(b * 12 + h);
          __bf16 bv = (__bf16)val;
          if (s == 0) {
            if constexpr (AUG) qo[bh * 49152 + (c >> 3) * 4096 + n * 8 + (c & 7)] = bv;
            else               qo[(bh * 512 + n) * 64 + c] = bv;
          } else if (s == 1) {
            if constexpr (AUG) ko[bh * 49152 + (c >> 3) * 4096 + n * 8 + (c & 7)] = bv;
            else               ko[(bh * 512 + n) * 64 + c] = bv;
          } else {
            vTo[(bh * (size_t)vstride + c) * 512 + n] = bv;
          }
        } else {
          outF[(size_t)row * N + col] = val;
        }
      }
    }
  }
}

// ================= Augmented-GEMM attention =================
// q_aug ch0..7 = Q; ch8..10 = 8*D_{d,h,w}[0..7]; ch11 = 0.
// k_aug ch0..7 = K; ch8..10 = onehot(kd),(kh),(kw); ch11 = 0.
// S = q_aug . k_aug^T ; P = exp2(S * 0.125 * LOG2E) == exp(0.125*QK + bias)
// vT_aug row 64 = ones -> PV col 64 = row-sums.

__global__ __launch_bounds__(256) void augment_kernel(
    __bf16* __restrict__ q_aug, __bf16* __restrict__ k_aug,
    const float* __restrict__ rpd, const float* __restrict__ rph,
    const float* __restrict__ rpw, __bf16* __restrict__ vT_aug) {
  const int bh = blockIdx.x >> 2, qt = blockIdx.x & 3;
  const int t = threadIdx.x;
  const int n0 = qt * 128;
  __bf16* qB = q_aug + (size_t)bh * 49152;
  __bf16* kB = k_aug + (size_t)bh * 49152;

  if (t < 128) {
    int n = n0 + t;
    bf16x8 z = {};
    *(bf16x8*)(qB + 11 * 4096 + n * 8) = z;
    *(bf16x8*)(kB + 11 * 4096 + n * 8) = z;
    bf16x8 z1 = {}, z2 = {}, z3 = {};
    z1[n >> 6]       = (__bf16)1.f;
    z2[(n >> 3) & 7] = (__bf16)1.f;
    z3[n & 7]        = (__bf16)1.f;
    *(bf16x8*)(kB + 8 * 4096 + n * 8)  = z1;
    *(bf16x8*)(kB + 9 * 4096 + n * 8)  = z2;
    *(bf16x8*)(kB + 10 * 4096 + n * 8) = z3;
    vT_aug[((size_t)bh * 80 + 64) * 512 + n] = (__bf16)1.f;
  }
  for (int o = t; o < 15 * 128; o += 256) {
    int rr = 65 + o / 128, n = n0 + (o & 127);
    vT_aug[((size_t)bh * 80 + rr) * 512 + n] = (__bf16)0.f;
  }
  // D dots -> q_aug cols 64..87 (x8 so the GEMM-wide 0.125 scale yields D)
  for (int o = t; o < 128 * 24; o += 256) {
    int row = o / 24, idx = o - row * 24;
    int n = n0 + row;
    const float* R;
    int d;
    if (idx < 8)       { d = (n >> 6)       - idx        + 7; R = rpd; }
    else if (idx < 16) { d = ((n >> 3) & 7) - (idx - 8)  + 7; R = rph; }
    else               { d = (n & 7)        - (idx - 16) + 7; R = rpw; }
    const float* Rr = R + d * 64;
    float s = 0.f;
#pragma unroll
    for (int c8 = 0; c8 < 8; ++c8) {
      bf16x8 qv = *(const bf16x8*)(qB + c8 * 4096 + n * 8);
      float4 r0 = *(const float4*)(Rr + c8 * 8);
      float4 r1 = *(const float4*)(Rr + c8 * 8 + 4);
      s += (float)qv[0] * r0.x + (float)qv[1] * r0.y + (float)qv[2] * r0.z + (float)qv[3] * r0.w;
      s += (float)qv[4] * r1.x + (float)qv[5] * r1.y + (float)qv[6] * r1.z + (float)qv[7] * r1.w;
    }
    qB[(8 + (idx >> 3)) * 4096 + n * 8 + (idx & 7)] = (__bf16)(8.f * s);
  }
}

// QK+exp: 128x128 tile per block, K=96 single pass. Chunk-major staging:
// global layout [ch][row][8] -> consecutive threads load consecutive rows (coalesced),
// LDS col-chunk layout [ch][128][8] -> fragment reads are 256B-contiguous (0 conflicts).
__global__ __launch_bounds__(256, 3) void qk_exp_kernel(
    const __bf16* __restrict__ q_aug, const __bf16* __restrict__ k_aug,
    __bf16* __restrict__ p_ws, int bh0) {
  __shared__ __attribute__((aligned(16))) __bf16 lA[12288];
  __shared__ __attribute__((aligned(16))) __bf16 lB[12288];
  const int t = threadIdx.x, l = t & 63, w = t >> 6;
  const int wm = (w >> 1) * 64, wn = (w & 1) * 64;
  const int wg = blockIdx.x;
  const int bhl = wg >> 4, qt = (wg >> 2) & 3, kt = wg & 3;
  const int bh = bh0 + bhl;

  const __bf16* As = q_aug + (size_t)bh * 49152 + qt * 1024;
  const __bf16* Bs = k_aug + (size_t)bh * 49152 + kt * 1024;
#pragma unroll
  for (int rnd = 0; rnd < 6; ++rnd) {
    int li = rnd * 256 + t;
    int ch = li >> 7, row = li & 127;
    gload_lds16(As + ch * 4096 + row * 8, lA + li * 8);
    gload_lds16(Bs + ch * 4096 + row * 8, lB + li * 8);
  }
  __syncthreads();

  f32x4 acc[4][4] = {};
#pragma unroll
  for (int s = 0; s < 3; ++s) {
    bf16x8 af[4], bfv[4];
    int ch = s * 4 + (l >> 4);
#pragma unroll
    for (int mt = 0; mt < 4; ++mt)
      af[mt] = *(const bf16x8*)(lA + (ch * 128 + wm + mt * 16 + (l & 15)) * 8);
#pragma unroll
    for (int nt = 0; nt < 4; ++nt)
      bfv[nt] = *(const bf16x8*)(lB + (ch * 128 + wn + nt * 16 + (l & 15)) * 8);
#pragma unroll
    for (int mt = 0; mt < 4; ++mt)
#pragma unroll
      for (int nt = 0; nt < 4; ++nt)
        acc[mt][nt] = mfma16(af[mt], bfv[nt], acc[mt][nt]);
  }

  const float scale2 = 0.125f * 1.44269504f;
  __bf16* pbase = p_ws + ((size_t)bhl * 512 + qt * 128) * 512 + kt * 128;
#pragma unroll
  for (int mt = 0; mt < 4; ++mt) {
#pragma unroll
    for (int nt = 0; nt < 4; ++nt) {
#pragma unroll
      for (int r = 0; r < 4; ++r) {
        int row = wm + mt * 16 + (l >> 4) * 4 + r;
        int col = wn + nt * 16 + (l & 15);
        pbase[(size_t)row * 512 + col] =
            (__bf16)__builtin_amdgcn_exp2f(acc[mt][nt][r] * scale2);
      }
    }
  }
}

// PV: per block 256 q-rows x 80 cols (0..63 = O, 64 = row-sum), K=512, 16 dbuf steps.
// LDS rows stride 32 elems with ^(row&3) chunk swizzle (both sides, rule #21).
__global__ __launch_bounds__(256, 3) void pv_kernel(
    const __bf16* __restrict__ p_ws, const __bf16* __restrict__ vT_aug,
    __bf16* __restrict__ attn_out, int bh0) {
  __shared__ __attribute__((aligned(16))) __bf16 lA[2][8192];
  __shared__ __attribute__((aligned(16))) __bf16 lB[2][2560];
  __shared__ float rs_inv[256];
  const int t = threadIdx.x, l = t & 63, w = t >> 6;
  const int wg = blockIdx.x;
  const int bhl = wg >> 1, m0 = (wg & 1) * 256;
  const int bh = bh0 + bhl;

  const __bf16* Abase = p_ws + ((size_t)bhl * 512 + m0) * 512;
  const __bf16* Bbase = vT_aug + (size_t)bh * 80 * 512;

  auto stage = [&](int buf, int kt) {
#pragma unroll
    for (int rnd = 0; rnd < 4; ++rnd) {
      int li = rnd * 256 + t;
      int row = li >> 2, pc = li & 3, lc = pc ^ (row & 3);
      gload_lds16(Abase + (size_t)row * 512 + kt * 32 + lc * 8, &lA[buf][li * 8]);
    }
    {
      int row = t >> 2, pc = t & 3, lc = pc ^ (row & 3);
      gload_lds16(Bbase + (size_t)row * 512 + kt * 32 + lc * 8, &lB[buf][t * 8]);
    }
    if (t < 64) {
      int li = 256 + t;
      int row = li >> 2, pc = li & 3, lc = pc ^ (row & 3);
      gload_lds16(Bbase + (size_t)row * 512 + kt * 32 + lc * 8, &lB[buf][li * 8]);
    }
  };

  f32x4 acc[4][5] = {};
  stage(0, 0);
  __syncthreads();
  int buf = 0;
  for (int kt = 0; kt < 16; ++kt) {
    if (kt + 1 < 16) stage(buf ^ 1, kt + 1);
    bf16x8 af[4], bfv[5];
#pragma unroll
    for (int mt = 0; mt < 4; ++mt) {
      int row = w * 64 + mt * 16 + (l & 15);
      af[mt] = *(const bf16x8*)(&lA[buf][(row * 4 + ((l >> 4) ^ (row & 3))) * 8]);
    }
#pragma unroll
    for (int nt = 0; nt < 5; ++nt) {
      int row = nt * 16 + (l & 15);
      bfv[nt] = *(const bf16x8*)(&lB[buf][(row * 4 + ((l >> 4) ^ (row & 3))) * 8]);
    }
#pragma unroll
    for (int mt = 0; mt < 4; ++mt)
#pragma unroll
      for (int nt = 0; nt < 5; ++nt)
        acc[mt][nt] = mfma16(af[mt], bfv[nt], acc[mt][nt]);
    __syncthreads();
    buf ^= 1;
  }

  if ((l & 15) == 0) {
#pragma unroll
    for (int mt = 0; mt < 4; ++mt)
#pragma unroll
      for (int r = 0; r < 4; ++r) {
        int row = w * 64 + mt * 16 + (l >> 4) * 4 + r;
        rs_inv[row] = 1.f / acc[mt][4][r];
      }
  }
  __syncthreads();

  const int b_ = bh / 12, h_ = bh - b_ * 12;
#pragma unroll
  for (int mt = 0; mt < 4; ++mt) {
#pragma unroll
    for (int r = 0; r < 4; ++r) {
      int rowl = w * 64 + mt * 16 + (l >> 4) * 4 + r;
      int n = m0 + rowl;
      float inv = rs_inv[rowl];
#pragma unroll
      for (int nt = 0; nt < 4; ++nt) {
        int d = nt * 16 + (l & 15);
        attn_out[((size_t)b_ * 512 + n) * 768 + h_ * 64 + d] = (__bf16)(acc[mt][nt][r] * inv);
      }
    }
  }
}

// ================= FALLBACK: R5 fused attention (validated, 184us) =================
__device__ __forceinline__ const bf16x8* kfrag(const __bf16* base, int row, int ch) {
  return (const bf16x8*)(base + row * 64 + ((ch ^ (row & 7)) * 8));
}
__device__ __forceinline__ const bf16x8* vfrag(const __bf16* base, int row, int ch) {
  return (const bf16x8*)(base + row * 32 + ((ch ^ ((row >> 1) & 3)) * 8));
}

__global__ __launch_bounds__(256, 4) void attn_kernel(
    const __bf16* __restrict__ qg_, const __bf16* __restrict__ kg,
    const __bf16* __restrict__ vT,
    const float* __restrict__ rpd, const float* __restrict__ rph,
    const float* __restrict__ rpw,
    __bf16* __restrict__ attn_out) {
  const int bid = (blockIdx.x & 7) * 192 + (blockIdx.x >> 3);
  const int bh = bid >> 2;
  const int qb = bid & 3;
  const int t = threadIdx.x, w = t >> 6, l = t & 63;
  const int lq = l & 31, lh5 = l >> 5;

  __shared__ float bias_lds[128][25];
  __shared__ float rs_lds[4][32];
  __shared__ __attribute__((aligned(16))) __bf16 k_lds[2][32 * 64];
  __shared__ __attribute__((aligned(16))) __bf16 v_lds[2][64 * 32];

  const __bf16* kb = kg + (size_t)bh * 512 * 64;
  const __bf16* vb = vT + (size_t)bh * 64 * 512;

  auto stage = [&](int sbuf, int j0) {
    {
      int row = t >> 3, pc = t & 7;
      int lc = pc ^ (row & 7);
      gload_lds16(kb + (size_t)(j0 + row) * 64 + lc * 8, &k_lds[sbuf][t * 8]);
    }
    {
      int row = t >> 2, pc = t & 3;
      int lc = pc ^ ((row >> 1) & 3);
      gload_lds16(vb + (size_t)row * 512 + j0 + lc * 8, &v_lds[sbuf][t * 8]);
    }
  };

  stage(0, 0);

  for (int o = t; o < 128 * 24; o += 256) {
    int row = o / 24, idx = o - row * 24;
    int n = qb * 128 + row;
    const __bf16* qrow = qg_ + ((size_t)bh * 512 + n) * 64;
    const float* R;
    int d;
    if (idx < 8)       { d = (n >> 6)       - idx        + 7; R = rpd; }
    else if (idx < 16) { d = ((n >> 3) & 7) - (idx - 8)  + 7; R = rph; }
    else               { d = (n & 7)        - (idx - 16) + 7; R = rpw; }
    const float* Rr = R + d * 64;
    float s = 0.f;
#pragma unroll
    for (int c8 = 0; c8 < 8; ++c8) {
      bf16x8 qv = *(const bf16x8*)(qrow + c8 * 8);
      float4 r0 = *(const float4*)(Rr + c8 * 8);
      float4 r1 = *(const float4*)(Rr + c8 * 8 + 4);
      s += (float)qv[0] * r0.x + (float)qv[1] * r0.y + (float)qv[2] * r0.z + (float)qv[3] * r0.w;
      s += (float)qv[4] * r1.x + (float)qv[5] * r1.y + (float)qv[6] * r1.z + (float)qv[7] * r1.w;
    }
    bias_lds[row][idx] = s;
  }

  const __bf16* qbase = qg_ + ((size_t)bh * 512 + qb * 128 + w * 32) * 64;
  bf16x8 qf[4];
#pragma unroll
  for (int s = 0; s < 4; ++s)
    qf[s] = *(const bf16x8*)(qbase + lq * 64 + s * 16 + lh5 * 8);

  __syncthreads();

  const float LOG2E = 1.44269504f;
  const float* brow = &bias_lds[w * 32 + lq][0];
  float bh2e[4], bh2o[4], bw2[4];
#pragma unroll
  for (int rr = 0; rr < 4; ++rr) {
    bh2e[rr] = brow[8 + rr] * LOG2E;
    bh2o[rr] = brow[12 + rr] * LOG2E;
    bw2[rr] = brow[16 + rr + 4 * lh5] * LOG2E;
  }

  f32x16 accO0 = {}, accO1 = {};
  float rs4[4] = {0.f, 0.f, 0.f, 0.f};
  const float scale2 = 0.125f * LOG2E;

  for (int kk = 0; kk < 8; ++kk) {
#pragma unroll
    for (int par = 0; par < 2; ++par) {
      const int kb_i = kk * 2 + par;
      if (kb_i < 15) stage(par ^ 1, (kb_i + 1) * 32);
      const __bf16* kl = k_lds[par];
      const __bf16* vl = v_lds[par];

      f32x16 accS = {};
#pragma unroll
      for (int s = 0; s < 4; ++s)
        accS = mfma32(*kfrag(kl, lq, lh5 + 2 * s), qf[s], accS);

      float bd2 = brow[kb_i >> 1] * LOG2E;
      float pr[16];
#pragma unroll
      for (int rr = 0; rr < 4; ++rr) {
        float bsum = bd2 + (par ? bh2o[rr] : bh2e[rr]);
#pragma unroll
        for (int c = 0; c < 4; ++c) {
          int r = rr * 4 + c;
          float p = __builtin_amdgcn_exp2f(accS[r] * scale2 + bsum + bw2[c]);
          rs4[rr] += p;
          pr[r] = p;
        }
      }

      unsigned a0 = cvtpk(pr[0], pr[1]),   b0 = cvtpk(pr[4], pr[5]);
      unsigned a1 = cvtpk(pr[2], pr[3]),   b1 = cvtpk(pr[6], pr[7]);
      unsigned a2 = cvtpk(pr[8], pr[9]),   b2 = cvtpk(pr[12], pr[13]);
      unsigned a3 = cvtpk(pr[10], pr[11]), b3 = cvtpk(pr[14], pr[15]);
      plswap(a0, b0); plswap(a1, b1); plswap(a2, b2); plswap(a3, b3);
      u32x4 u0 = {a0, a1, b0, b1};
      u32x4 u1 = {a2, a3, b2, b3};
      bf16x8 pf0 = __builtin_bit_cast(bf16x8, u0);
      bf16x8 pf1 = __builtin_bit_cast(bf16x8, u1);

      accO0 = mfma32(pf0, *vfrag(vl, lq, lh5), accO0);
      accO0 = mfma32(pf1, *vfrag(vl, lq, lh5 + 2), accO0);
      accO1 = mfma32(pf0, *vfrag(vl, 32 + lq, lh5), accO1);
      accO1 = mfma32(pf1, *vfrag(vl, 32 + lq, lh5 + 2), accO1);

      __syncthreads();
    }
  }

  {
    float rsum = (rs4[0] + rs4[1]) + (rs4[2] + rs4[3]);
    float s = rsum + __shfl_xor(rsum, 32);
    if (l < 32) rs_lds[w][l] = 1.f / s;
  }

  const int b_ = bh / 12, h_ = bh - b_ * 12;
  __bf16* obase = attn_out + ((size_t)b_ * 512 + qb * 128 + w * 32) * 768 + h_ * 64;
#pragma unroll
  for (int rr = 0; rr < 4; ++rr) {
#pragma unroll
    for (int c = 0; c < 4; ++c) {
      int r = rr * 4 + c;
      int qrow = c + 8 * rr + 4 * lh5;
      float inv = rs_lds[w][qrow];
      obase[(size_t)qrow * 768 + lq]      = (__bf16)(accO0[r] * inv);
      obase[(size_t)qrow * 768 + 32 + lq] = (__bf16)(accO1[r] * inv);
    }
  }
}

extern "C" void kernel_launch(void* const* d_in, const int* in_sizes, int n_in,
                              void* d_out, int out_size, void* d_ws, size_t ws_size,
                              hipStream_t stream) {
  const float* x      = (const float*)d_in[0];
  const float* w_qkv  = (const float*)d_in[1];
  const float* b_qkv  = (const float*)d_in[2];
  const float* w_proj = (const float*)d_in[3];
  const float* b_proj = (const float*)d_in[4];
  const float* rpd    = (const float*)d_in[5];
  const float* rph    = (const float*)d_in[6];
  const float* rpw    = (const float*)d_in[7];
  float* out = (float*)d_out;

  char* base = (char*)d_ws;
  __bf16* xb     = (__bf16*)(base);               // 25,165,824 (x bf16; reused as attn_out)
  __bf16* wqkvT  = (__bf16*)(base + 25165824);    // 3,538,944
  __bf16* wprojT = (__bf16*)(base + 28704768);    // 1,179,648

  // tier selection: fixed aug part ends at 136,839,168; P chunk = CH*512*512*2
  const size_t FIXED = 136839168ull;
  int CH = 0;
  if      (ws_size >= FIXED + 201326592ull) CH = 384;
  else if (ws_size >= FIXED + 100663296ull) CH = 192;
  else if (ws_size >= FIXED + 50331648ull)  CH = 96;
  else if (ws_size >= FIXED + 25165824ull)  CH = 48;
  const bool big = CH > 0;

  cvt_bf16_kernel<<<12288, 256, 0, stream>>>(x, xb, 12582912 / 4);
  transpose_cvt_kernel<<<dim3(2304 / 32, 768 / 32), 256, 0, stream>>>(w_qkv, wqkvT, 768, 2304);
  transpose_cvt_kernel<<<dim3(768 / 32, 768 / 32), 256, 0, stream>>>(w_proj, wprojT, 768, 768);

  if (big) {
    __bf16* qA  = (__bf16*)(base + 29884416);     // 37,748,736 (chunk-major aug)
    __bf16* kA  = (__bf16*)(base + 67633152);     // 37,748,736
    __bf16* vT  = (__bf16*)(base + 105381888);    // 31,457,280 (80 rows)
    __bf16* pws = (__bf16*)(base + 136839168);    // CH * 524,288 B

    gemm_bt_kernel<0, 1><<<2304, 256, 0, stream>>>(
        xb, wqkvT, 16384, 2304, 768, 18, b_qkv, nullptr, qA, kA, vT, 80);
    augment_kernel<<<1536, 256, 0, stream>>>(qA, kA, rpd, rph, rpw, vT);
    for (int c0 = 0; c0 < 384; c0 += CH) {
      qk_exp_kernel<<<CH * 16, 256, 0, stream>>>(qA, kA, pws, c0);
      pv_kernel<<<CH * 2, 256, 0, stream>>>(pws, vT, xb, c0);
    }
  } else {
    __bf16* qb_ = (__bf16*)(base + 29884416);     // 25,165,824 (row-major 64)
    __bf16* kb_ = (__bf16*)(base + 55050240);     // 25,165,824
    __bf16* vT  = (__bf16*)(base + 80216064);     // 25,165,824 (64 rows)

    gemm_bt_kernel<0, 0><<<2304, 256, 0, stream>>>(
        xb, wqkvT, 16384, 2304, 768, 18, b_qkv, nullptr, qb_, kb_, vT, 64);
    attn_kernel<<<1536, 256, 0, stream>>>(qb_, kb_, vT, rpd, rph, rpw, xb);
  }

  gemm_bt_kernel<1, 0><<<768, 256, 0, stream>>>(
      xb, wprojT, 16384, 768, 768, 6, b_proj, out, nullptr, nullptr, nullptr, 64);
}

// Round 10
// 200.078 us; speedup vs baseline: 2.1749x; 2.1749x over previous
//
#include <hip/hip_runtime.h>
#include <hip/hip_bf16.h>
#include <cstdint>

typedef __bf16 bf16x8 __attribute__((ext_vector_type(8)));
typedef __bf16 bf16x4 __attribute__((ext_vector_type(4)));
typedef float  f32x4  __attribute__((ext_vector_type(4)));
typedef float  f32x16 __attribute__((ext_vector_type(16)));
typedef unsigned u32x4 __attribute__((ext_vector_type(4)));

__device__ __forceinline__ f32x4 mfma16(bf16x8 a, bf16x8 b, f32x4 c) {
  return __builtin_amdgcn_mfma_f32_16x16x32_bf16(a, b, c, 0, 0, 0);
}
__device__ __forceinline__ f32x16 mfma32(bf16x8 a, bf16x8 b, f32x16 c) {
  return __builtin_amdgcn_mfma_f32_32x32x16_bf16(a, b, c, 0, 0, 0);
}

__device__ __forceinline__ void gload_lds16(const __bf16* g, __bf16* l) {
  __builtin_amdgcn_global_load_lds(
      (const __attribute__((address_space(1))) void*)g,
      (__attribute__((address_space(3))) void*)l, 16, 0, 0);
}

__device__ __forceinline__ unsigned cvtpk(float lo, float hi) {
  unsigned r;
  asm("v_cvt_pk_bf16_f32 %0, %1, %2" : "=v"(r) : "v"(lo), "v"(hi));
  return r;
}
// lane<32 halves swap between a and b
__device__ __forceinline__ void plswap(unsigned& a, unsigned& b) {
  asm("v_permlane32_swap_b32 %0, %1" : "+v"(a), "+v"(b));
}

// ---------------- fp32 -> bf16 convert (x4 per thread) ----------------
__global__ __launch_bounds__(256) void cvt_bf16_kernel(const float* __restrict__ in,
                                                       __bf16* __restrict__ out, int n4) {
  int i = blockIdx.x * 256 + threadIdx.x;
  if (i < n4) {
    float4 v = ((const float4*)in)[i];
    bf16x4 o;
    o[0] = (__bf16)v.x; o[1] = (__bf16)v.y; o[2] = (__bf16)v.z; o[3] = (__bf16)v.w;
    ((bf16x4*)out)[i] = o;
  }
}

// ------------- transpose + cvt: src (R x C) f32 -> dst (C x R) bf16 -------------
__global__ __launch_bounds__(256) void transpose_cvt_kernel(const float* __restrict__ src,
                                                            __bf16* __restrict__ dst,
                                                            int R, int C) {
  __shared__ float tile[32][33];
  int r0 = blockIdx.y * 32, c0 = blockIdx.x * 32;
  int tx = threadIdx.x & 31, ty = threadIdx.x >> 5;
#pragma unroll
  for (int i = 0; i < 4; ++i)
    tile[ty + i * 8][tx] = src[(size_t)(r0 + ty + i * 8) * C + c0 + tx];
  __syncthreads();
#pragma unroll
  for (int i = 0; i < 4; ++i) {
    int rr = ty + i * 8;
    dst[(size_t)(c0 + rr) * R + r0 + tx] = (__bf16)tile[tx][rr];
  }
}

// ------------- bf16 GEMM, A (MxK) row-major, Bt (NxK) row-major = B^T -------------
template <int EPI>
__global__ __launch_bounds__(256) void gemm_bt_kernel(
    const __bf16* __restrict__ A, const __bf16* __restrict__ Bt,
    int M, int N, int K, int nbx,
    const float* __restrict__ bias,
    float* __restrict__ outF,
    __bf16* __restrict__ qo, __bf16* __restrict__ ko, __bf16* __restrict__ vTo) {
  __shared__ __attribute__((aligned(16))) __bf16 lds[2][2][4096];  // [buf][A/B][128*32]
  const int t = threadIdx.x;
  const int l = t & 63, w = t >> 6;
  const int wm = (w >> 1) * 64, wn = (w & 1) * 64;
  const int cpx = gridDim.x >> 3;
  const int wg = (blockIdx.x & 7) * cpx + (blockIdx.x >> 3);
  const int m0 = (wg / nbx) * 128, n0 = (wg % nbx) * 128;
  const int nk = K >> 5;

  auto stage = [&](int buf, int kt) {
    const __bf16* As = A + (size_t)m0 * K + kt * 32;
    const __bf16* Bs = Bt + (size_t)n0 * K + kt * 32;
#pragma unroll
    for (int rnd = 0; rnd < 2; ++rnd) {
      int li = rnd * 256 + t;
      int row = li >> 2, c8 = (li & 3) * 8;
      gload_lds16(As + (size_t)row * K + c8, &lds[buf][0][li * 8]);
      gload_lds16(Bs + (size_t)row * K + c8, &lds[buf][1][li * 8]);
    }
  };

  f32x4 acc[4][4] = {};
  stage(0, 0);
  __syncthreads();
  int buf = 0;
  for (int kt = 0; kt < nk; ++kt) {
    if (kt + 1 < nk) stage(buf ^ 1, kt + 1);
    bf16x8 af[4], bfv[4];
    const __bf16* la = &lds[buf][0][0];
    const __bf16* lb = &lds[buf][1][0];
#pragma unroll
    for (int mt = 0; mt < 4; ++mt)
      af[mt] = *(const bf16x8*)(la + (wm + mt * 16 + (l & 15)) * 32 + (l >> 4) * 8);
#pragma unroll
    for (int nt = 0; nt < 4; ++nt)
      bfv[nt] = *(const bf16x8*)(lb + (wn + nt * 16 + (l & 15)) * 32 + (l >> 4) * 8);
#pragma unroll
    for (int mt = 0; mt < 4; ++mt)
#pragma unroll
      for (int nt = 0; nt < 4; ++nt)
        acc[mt][nt] = mfma16(af[mt], bfv[nt], acc[mt][nt]);
    __syncthreads();
    buf ^= 1;
  }

#pragma unroll
  for (int mt = 0; mt < 4; ++mt) {
#pragma unroll
    for (int nt = 0; nt < 4; ++nt) {
#pragma unroll
      for (int r = 0; r < 4; ++r) {
        int row = m0 + wm + mt * 16 + (l >> 4) * 4 + r;
        int col = n0 + wn + nt * 16 + (l & 15);
        float val = acc[mt][nt][r] + bias[col];
        if constexpr (EPI == 0) {
          int s = col / 768, rem = col - s * 768;
          int h = rem >> 6, c = rem & 63;
          int b = row >> 9, n = row & 511;
          size_t bh = (size_t)(b * 12 + h);
          __bf16 bv = (__bf16)val;
          if (s == 0)      qo[(bh * 512 + n) * 64 + c] = bv;
          else if (s == 1) ko[(bh * 512 + n) * 64 + c] = bv;
          else             vTo[(bh * 64 + c) * 512 + n] = bv;
        } else {
          outF[(size_t)row * N + col] = val;
        }
      }
    }
  }
}

// ------------- fused attention, QBLK=128, KVBLK=32, 32x32 MFMA, in-reg P -------------
// Bias precompute via MFMA: C[j][q] = dot(Rcat[j], q) with
// Rcat rows: jt=0: 0..14 = rpd, 16..30 = rph (15,31 zero); jt=1: 0..14 = rpw.
// C/D layout (validated): j = (r&3)+8*(r>>2)+4*lh5, q = lq -> predicated scatter
// into bias_lds[row][0..23]; out-of-range idx drops the zero/junk rows.
// Main loop identical to R5/R9-validated kernel (in-reg P, cvt_pk+permlane).
__device__ __forceinline__ const bf16x8* kfrag(const __bf16* base, int row, int ch) {
  return (const bf16x8*)(base + row * 64 + ((ch ^ (row & 7)) * 8));
}
__device__ __forceinline__ const bf16x8* vfrag(const __bf16* base, int row, int ch) {
  return (const bf16x8*)(base + row * 32 + ((ch ^ ((row >> 1) & 3)) * 8));
}

__global__ __launch_bounds__(256, 4) void attn_kernel(
    const __bf16* __restrict__ qg_, const __bf16* __restrict__ kg,
    const __bf16* __restrict__ vT,
    const float* __restrict__ rpd, const float* __restrict__ rph,
    const float* __restrict__ rpw,
    __bf16* __restrict__ attn_out) {
  // XCD swizzle: 1536 blocks = 8 x 192
  const int bid = (blockIdx.x & 7) * 192 + (blockIdx.x >> 3);
  const int bh = bid >> 2;
  const int qb = bid & 3;
  const int t = threadIdx.x, w = t >> 6, l = t & 63;
  const int lq = l & 31, lh5 = l >> 5;

  __shared__ float bias_lds[128][25];
  __shared__ float rs_lds[4][32];
  __shared__ __attribute__((aligned(16))) __bf16 k_lds[2][32 * 64];
  __shared__ __attribute__((aligned(16))) __bf16 v_lds[2][64 * 32];

  const __bf16* kb = kg + (size_t)bh * 512 * 64;
  const __bf16* vb = vT + (size_t)bh * 64 * 512;

  auto stage = [&](int sbuf, int j0) {
    {
      int row = t >> 3, pc = t & 7;
      int lc = pc ^ (row & 7);
      gload_lds16(kb + (size_t)(j0 + row) * 64 + lc * 8, &k_lds[sbuf][t * 8]);
    }
    {
      int row = t >> 2, pc = t & 3;
      int lc = pc ^ ((row >> 1) & 3);
      gload_lds16(vb + (size_t)row * 512 + j0 + lc * 8, &v_lds[sbuf][t * 8]);
    }
  };

  stage(0, 0);

  // Q fragments (B-operand): lane holds Q[q=lq][k = s*16 + lh5*8 + j]
  const __bf16* qbase = qg_ + ((size_t)bh * 512 + qb * 128 + w * 32) * 64;
  bf16x8 qf[4];
#pragma unroll
  for (int s = 0; s < 4; ++s)
    qf[s] = *(const bf16x8*)(qbase + lq * 64 + s * 16 + lh5 * 8);

  // ---- bias precompute via MFMA ----
  {
    const int row = w * 32 + lq;
    const int n = qb * 128 + row;
    const int dd = n >> 6, hh = (n >> 3) & 7, ww = n & 7;
#pragma unroll
    for (int jt = 0; jt < 2; ++jt) {
      const float* src;
      if (jt == 0) src = (lq < 15) ? rpd + (size_t)lq * 64
                                   : (lq >= 16 && lq < 31) ? rph + (size_t)(lq - 16) * 64
                                                           : nullptr;
      else         src = (lq < 15) ? rpw + (size_t)lq * 64 : nullptr;
      f32x16 cb = {};
#pragma unroll
      for (int s = 0; s < 4; ++s) {
        bf16x8 afr;
        if (src) {
          float4 a = *(const float4*)(src + s * 16 + lh5 * 8);
          float4 b = *(const float4*)(src + s * 16 + lh5 * 8 + 4);
          u32x4 u = {cvtpk(a.x, a.y), cvtpk(a.z, a.w), cvtpk(b.x, b.y), cvtpk(b.z, b.w)};
          afr = __builtin_bit_cast(bf16x8, u);
        } else {
          afr = bf16x8{};
        }
        cb = mfma32(afr, qf[s], cb);
      }
#pragma unroll
      for (int r = 0; r < 16; ++r) {
        int j = (r & 3) + 8 * (r >> 2) + 4 * lh5;  // 0..31 within this jt
        if (jt == 0) {
          if (j < 16) {
            int idx = dd + 7 - j;
            if (idx >= 0 && idx < 8) bias_lds[row][idx] = cb[r];
          } else {
            int idx = hh + 7 - (j - 16);
            if (idx >= 0 && idx < 8) bias_lds[row][8 + idx] = cb[r];
          }
        } else {
          if (j < 16) {
            int idx = ww + 7 - j;
            if (idx >= 0 && idx < 8) bias_lds[row][16 + idx] = cb[r];
          }
        }
      }
    }
  }

  __syncthreads();  // stage(0) drained; bias rows are wave-local but keep one barrier

  // hoist bias into registers (exp2 domain). key = 32*kbk + (r&3) + 8*(r>>2) + 4*lh5:
  const float LOG2E = 1.44269504f;
  const float* brow = &bias_lds[w * 32 + lq][0];
  float bh2e[4], bh2o[4], bw2[4];
#pragma unroll
  for (int rr = 0; rr < 4; ++rr) {
    bh2e[rr] = brow[8 + rr] * LOG2E;
    bh2o[rr] = brow[12 + rr] * LOG2E;
    bw2[rr] = brow[16 + rr + 4 * lh5] * LOG2E;
  }

  f32x16 accO0 = {}, accO1 = {};
  float rs4[4] = {0.f, 0.f, 0.f, 0.f};
  const float scale2 = 0.125f * LOG2E;

  for (int kk = 0; kk < 8; ++kk) {
#pragma unroll
    for (int par = 0; par < 2; ++par) {
      const int kb_i = kk * 2 + par;
      if (kb_i < 15) stage(par ^ 1, (kb_i + 1) * 32);
      const __bf16* kl = k_lds[par];
      const __bf16* vl = v_lds[par];

      f32x16 accS = {};
#pragma unroll
      for (int s = 0; s < 4; ++s)
        accS = mfma32(*kfrag(kl, lq, lh5 + 2 * s), qf[s], accS);

      float bd2 = brow[kb_i >> 1] * LOG2E;
      float pr[16];
#pragma unroll
      for (int rr = 0; rr < 4; ++rr) {
        float bsum = bd2 + (par ? bh2o[rr] : bh2e[rr]);
#pragma unroll
        for (int c = 0; c < 4; ++c) {
          int r = rr * 4 + c;
          float p = __builtin_amdgcn_exp2f(accS[r] * scale2 + bsum + bw2[c]);
          rs4[rr] += p;
          pr[r] = p;
        }
      }

      unsigned a0 = cvtpk(pr[0], pr[1]),   b0 = cvtpk(pr[4], pr[5]);
      unsigned a1 = cvtpk(pr[2], pr[3]),   b1 = cvtpk(pr[6], pr[7]);
      unsigned a2 = cvtpk(pr[8], pr[9]),   b2 = cvtpk(pr[12], pr[13]);
      unsigned a3 = cvtpk(pr[10], pr[11]), b3 = cvtpk(pr[14], pr[15]);
      plswap(a0, b0); plswap(a1, b1); plswap(a2, b2); plswap(a3, b3);
      u32x4 u0 = {a0, a1, b0, b1};
      u32x4 u1 = {a2, a3, b2, b3};
      bf16x8 pf0 = __builtin_bit_cast(bf16x8, u0);
      bf16x8 pf1 = __builtin_bit_cast(bf16x8, u1);

      accO0 = mfma32(pf0, *vfrag(vl, lq, lh5), accO0);
      accO0 = mfma32(pf1, *vfrag(vl, lq, lh5 + 2), accO0);
      accO1 = mfma32(pf0, *vfrag(vl, 32 + lq, lh5), accO1);
      accO1 = mfma32(pf1, *vfrag(vl, 32 + lq, lh5 + 2), accO1);

      __syncthreads();
    }
  }

  {
    float rsum = (rs4[0] + rs4[1]) + (rs4[2] + rs4[3]);
    float s = rsum + __shfl_xor(rsum, 32);
    if (l < 32) rs_lds[w][l] = 1.f / s;
  }

  const int b_ = bh / 12, h_ = bh - b_ * 12;
  __bf16* obase = attn_out + ((size_t)b_ * 512 + qb * 128 + w * 32) * 768 + h_ * 64;
#pragma unroll
  for (int rr = 0; rr < 4; ++rr) {
#pragma unroll
    for (int c = 0; c < 4; ++c) {
      int r = rr * 4 + c;
      int qrow = c + 8 * rr + 4 * lh5;
      float inv = rs_lds[w][qrow];
      obase[(size_t)qrow * 768 + lq]      = (__bf16)(accO0[r] * inv);
      obase[(size_t)qrow * 768 + 32 + lq] = (__bf16)(accO1[r] * inv);
    }
  }
}

extern "C" void kernel_launch(void* const* d_in, const int* in_sizes, int n_in,
                              void* d_out, int out_size, void* d_ws, size_t ws_size,
                              hipStream_t stream) {
  const float* x      = (const float*)d_in[0];
  const float* w_qkv  = (const float*)d_in[1];
  const float* b_qkv  = (const float*)d_in[2];
  const float* w_proj = (const float*)d_in[3];
  const float* b_proj = (const float*)d_in[4];
  const float* rpd    = (const float*)d_in[5];
  const float* rph    = (const float*)d_in[6];
  const float* rpw    = (const float*)d_in[7];
  float* out = (float*)d_out;

  char* base = (char*)d_ws;
  __bf16* xb     = (__bf16*)(base);                                  // 16384x768 bf16; reused as attn_out
  __bf16* wqkvT  = (__bf16*)(base + 25165824);                       // 2304x768
  __bf16* wprojT = (__bf16*)(base + 25165824 + 3538944);             // 768x768
  __bf16* qb     = (__bf16*)(base + 25165824 + 3538944 + 1179648);   // 384x512x64
  __bf16* kb     = qb + (size_t)384 * 512 * 64;
  __bf16* vT     = kb + (size_t)384 * 512 * 64;

  cvt_bf16_kernel<<<12288, 256, 0, stream>>>(x, xb, 12582912 / 4);
  transpose_cvt_kernel<<<dim3(2304 / 32, 768 / 32), 256, 0, stream>>>(w_qkv, wqkvT, 768, 2304);
  transpose_cvt_kernel<<<dim3(768 / 32, 768 / 32), 256, 0, stream>>>(w_proj, wprojT, 768, 768);

  gemm_bt_kernel<0><<<2304, 256, 0, stream>>>(
      xb, wqkvT, 16384, 2304, 768, 18, b_qkv, nullptr, qb, kb, vT);

  attn_kernel<<<1536, 256, 0, stream>>>(qb, kb, vT, rpd, rph, rpw, xb);

  gemm_bt_kernel<1><<<768, 256, 0, stream>>>(
      xb, wprojT, 16384, 768, 768, 6, b_proj, out, nullptr, nullptr, nullptr);
}